// Round 2
// baseline (43385.638 us; speedup 1.0000x reference)
//
#include <hip/hip_runtime.h>

// Persistent 2-layer LSTM for MI355X (gfx950).
// 256 WGs x 256 threads (plain launch; 256 blocks <= 256 CUs => all resident).
// Each WG owns 4 hidden units (16 gate rows: 4 units x {i,f,g,o}).
// Weights pinned in VGPRs as bf16 MFMA fragments. Grid barrier per timestep.

typedef unsigned short ushort_t;
typedef __attribute__((ext_vector_type(8))) short short8;   // 8 bf16 (4 VGPRs) MFMA operand
typedef __attribute__((ext_vector_type(4))) float f32x4;

#define NWG    256
#define SEQ    512
#define HSLOT  32768          // 32*1024 elements per time slot
#define FULLSLOTS 513         // slot 0 = zeros, slot t+1 = h after step t

__device__ __forceinline__ ushort_t f2bf(float f) {
  unsigned u = __builtin_bit_cast(unsigned, f);
  u += 0x7FFFu + ((u >> 16) & 1u);      // round-to-nearest-even
  return (ushort_t)(u >> 16);
}

__device__ __forceinline__ short8 pack_bf8(f32x4 a, f32x4 b) {
  short8 r;
  r[0] = (short)f2bf(a[0]); r[1] = (short)f2bf(a[1]);
  r[2] = (short)f2bf(a[2]); r[3] = (short)f2bf(a[3]);
  r[4] = (short)f2bf(b[0]); r[5] = (short)f2bf(b[1]);
  r[6] = (short)f2bf(b[2]); r[7] = (short)f2bf(b[3]);
  return r;
}

__device__ __forceinline__ float sigm(float x) { return 1.0f / (1.0f + __expf(-x)); }
__device__ __forceinline__ float fast_tanh(float x) {
  x = fminf(fmaxf(x, -15.f), 15.f);          // avoid inf/inf -> NaN
  float e = __expf(-2.0f * x);
  return (1.0f - e) / (1.0f + e);
}

// Grid barrier: 8 striped monotonic counters (128 B apart).
// __threadfence() on both sides = agent-scope WB/INV per the HIP memory model
// (handles the 8 non-coherent per-XCD L2s). Spin is BOUNDED so a coherence or
// residency failure degrades to a wrong answer instead of a hung container.
__device__ __forceinline__ void gsync(unsigned* cnt, unsigned epoch) {
  __syncthreads();
  __threadfence();   // release: publish this WG's h-stores device-wide
  if (threadIdx.x == 0)
    __hip_atomic_fetch_add(cnt + (blockIdx.x & 7) * 32, 1u,
                           __ATOMIC_RELAXED, __HIP_MEMORY_SCOPE_AGENT);
  if (threadIdx.x < 8) {
    const unsigned tgt = epoch * (NWG / 8);
    for (int it = 0; it < 65536; ++it) {
      if (__hip_atomic_load(cnt + threadIdx.x * 32,
                            __ATOMIC_RELAXED, __HIP_MEMORY_SCOPE_AGENT) >= tgt) break;
      __builtin_amdgcn_s_sleep(1);
    }
  }
  __syncthreads();
  __threadfence();   // acquire: invalidate stale lines before consuming h
}

// One LSTM layer over 512 steps.
//  KX    : K-extent of the x-part (512 for layer0, 1024 for layer1)
//  NCHX  : x-part K-chunks (KX/32)
//  XFP32 : x-part source is fp32 (layer0 reads x directly), else bf16
// Wave roles: ntile = wave&1 (batch 16-tile), khalf = wave>>1 (0: x-part K, 1: h-part K).
// MFMA: D[m][n] = sum_k Wslice[m][k]*act[n][k]; m (= A row) = unit_local*4+gate, n = batch.
// C/D layout: col = lane&15 (=batch), row = (lane>>4)*4 + reg  -> reg = gate.
template<int KX, int NCHX, bool XFP32>
__device__ __forceinline__ void run_layer(
    const void* xsrc, long x_step, long x_bstride,
    const ushort_t* __restrict__ hbuf, ushort_t* __restrict__ hbuf_w, unsigned hmask,
    const float* __restrict__ W, int ldw,
    const float* __restrict__ bias,
    float* __restrict__ out, int out_h_off, int out_c_off, int write_last,
    float* red, unsigned* cnt, unsigned& epoch, int unit_base)
{
  const int lane  = threadIdx.x & 63;
  const int wave  = threadIdx.x >> 6;
  const int ntile = wave & 1;
  const int khalf = wave >> 1;
  const int wrow  = lane & 15;                      // A-frag row (gate slot m)
  const int koff  = (lane >> 4) * 8;                // A/B-frag k offset
  const int bb    = ntile * 16 + (lane & 15);       // batch (B row / D col)
  const int u     = unit_base + (lane >> 4);        // hidden unit for epilogue
  const int grow  = (wrow & 3) * 1024 + unit_base + (wrow >> 2); // W row: gate*1024+unit

  // ---- pin this wave's weight fragments in registers (bf16) ----
  short8 wreg[32];
  {
    const int kbase = khalf ? KX : 0;
    const int mych  = khalf ? 32 : NCHX;
    const float* ws = W + (long)grow * ldw + kbase + koff;
    #pragma unroll
    for (int ch = 0; ch < 32; ++ch) {
      if (ch < mych) {
        f32x4 v0 = *(const f32x4*)(ws + ch * 32);
        f32x4 v1 = *(const f32x4*)(ws + ch * 32 + 4);
        wreg[ch] = pack_bf8(v0, v1);
      }
    }
  }

  const float bI = bias[u];
  const float bF = bias[1024 + u];
  const float bG = bias[2048 + u];
  const float bO = bias[3072 + u];
  float c = 0.0f;

  for (int t = 0; t < SEQ; ++t) {
    f32x4 acc0 = {0.f, 0.f, 0.f, 0.f};
    f32x4 acc1 = {0.f, 0.f, 0.f, 0.f};

    if (khalf == 0) {
      if constexpr (XFP32) {
        const float* bp = (const float*)xsrc + (long)t * x_step + (long)bb * x_bstride + koff;
        #pragma unroll
        for (int ch = 0; ch < NCHX; ++ch) {
          f32x4 v0 = *(const f32x4*)(bp + ch * 32);
          f32x4 v1 = *(const f32x4*)(bp + ch * 32 + 4);
          short8 bfrag = pack_bf8(v0, v1);
          if (ch & 1) acc1 = __builtin_amdgcn_mfma_f32_16x16x32_bf16(wreg[ch], bfrag, acc1, 0, 0, 0);
          else        acc0 = __builtin_amdgcn_mfma_f32_16x16x32_bf16(wreg[ch], bfrag, acc0, 0, 0, 0);
        }
      } else {
        const ushort_t* bp = (const ushort_t*)xsrc + (long)t * x_step + (long)bb * x_bstride + koff;
        #pragma unroll
        for (int ch = 0; ch < NCHX; ++ch) {
          short8 bfrag = *(const short8*)(bp + ch * 32);
          if (ch & 1) acc1 = __builtin_amdgcn_mfma_f32_16x16x32_bf16(wreg[ch], bfrag, acc1, 0, 0, 0);
          else        acc0 = __builtin_amdgcn_mfma_f32_16x16x32_bf16(wreg[ch], bfrag, acc0, 0, 0, 0);
        }
      }
    } else {
      // recurrent part: h_prev = hbuf slot (t & hmask)
      const ushort_t* bp = hbuf + (long)(t & hmask) * HSLOT + bb * 1024 + koff;
      #pragma unroll
      for (int ch = 0; ch < 32; ++ch) {
        short8 bfrag = *(const short8*)(bp + ch * 32);
        if (ch & 1) acc1 = __builtin_amdgcn_mfma_f32_16x16x32_bf16(wreg[ch], bfrag, acc1, 0, 0, 0);
        else        acc0 = __builtin_amdgcn_mfma_f32_16x16x32_bf16(wreg[ch], bfrag, acc0, 0, 0, 0);
      }
      f32x4 acc = acc0 + acc1;
      *(f32x4*)&red[(ntile * 64 + lane) * 4] = acc;  // partial for cross-wave K-reduction
    }

    __syncthreads();

    if (khalf == 0) {
      f32x4 acc = acc0 + acc1;
      f32x4 oth = *(const f32x4*)&red[(ntile * 64 + lane) * 4];
      float pi = acc[0] + oth[0] + bI;
      float pf = acc[1] + oth[1] + bF;
      float pg = acc[2] + oth[2] + bG;
      float po = acc[3] + oth[3] + bO;
      float ig = sigm(pi);
      float fg = sigm(pf);
      float gg = fast_tanh(pg);
      float og = sigm(po);
      c = fg * c + ig * gg;
      float h = og * fast_tanh(c);
      hbuf_w[(long)((t + 1) & hmask) * HSLOT + bb * 1024 + u] = f2bf(h);
      if (t == SEQ - 1) {
        out[out_h_off + bb * 1024 + u] = h;      // h_n[layer]
        out[out_c_off + bb * 1024 + u] = c;      // c_n[layer]
        if (write_last) out[bb * 1024 + u] = h;  // out1[:, -1, :]
      }
    }

    ++epoch;
    gsync(cnt, epoch);
  }
}

__global__ __launch_bounds__(256, 1)
void lstm_persistent(const float* __restrict__ x,  const float* __restrict__ W0,
                     const float* __restrict__ b0, const float* __restrict__ W1,
                     const float* __restrict__ b1, float* __restrict__ out,
                     unsigned* cnt, ushort_t* O0, ushort_t* H1, unsigned h1_mask)
{
  __shared__ float red[512];   // cross-wave K-reduction: 2 ntiles x 64 lanes x 4 floats
  unsigned epoch = 0;
  const int unit_base = blockIdx.x * 4;

  // zero slot 0 of both h buffers (initial hidden state)
  int gtid = blockIdx.x * 256 + threadIdx.x;
  if (gtid < 16384) {
    ((unsigned*)O0)[gtid] = 0u;   // 16384 u32 = 32768 bf16 = one slot
    ((unsigned*)H1)[gtid] = 0u;
  }
  ++epoch;
  gsync(cnt, epoch);

  // layer 0: combined = [x_t (fp32, K=512) ; h0_prev (bf16, K=1024)]
  // O0 is full-indexed (layer 1 consumes every slot).
  run_layer<512, 16, true>(x, 512, 262144,
                           O0, O0, 0xFFFFFFFFu, W0, 1536, b0,
                           out, 32768, 98304, 0,
                           red, cnt, epoch, unit_base);

  // layer 1: combined = [out0_t (= O0 slot t+1, K=1024) ; h1_prev (bf16, K=1024)]
  run_layer<1024, 32, false>((const void*)(O0 + HSLOT), HSLOT, 1024,
                             H1, H1, h1_mask, W1, 2048, b1,
                             out, 65536, 131072, 1,
                             red, cnt, epoch, unit_base);
}

extern "C" void kernel_launch(void* const* d_in, const int* in_sizes, int n_in,
                              void* d_out, int out_size, void* d_ws, size_t ws_size,
                              hipStream_t stream) {
  (void)in_sizes; (void)n_in; (void)out_size;

  const float* x  = (const float*)d_in[0];
  const float* W0 = (const float*)d_in[1];
  const float* b0 = (const float*)d_in[2];
  const float* W1 = (const float*)d_in[3];
  const float* b1 = (const float*)d_in[4];
  float* out = (float*)d_out;

  // workspace layout:
  //   [0, 1024)                      barrier counters (8 stripes x 128 B)
  //   [1024, +513*64KB)              O0: layer-0 h, full 513 slots (write-once)
  //   then H1: layer-1 h, 513 slots if ws allows, else 2-slot ping-pong
  const size_t o0_bytes   = (size_t)FULLSLOTS * HSLOT * sizeof(ushort_t);
  const size_t need_full  = 1024 + o0_bytes + o0_bytes;
  const size_t need_pp    = 1024 + o0_bytes + 2ull * HSLOT * sizeof(ushort_t);

  unsigned h1_mask;
  if      (ws_size >= need_full) h1_mask = 0xFFFFFFFFu;
  else if (ws_size >= need_pp)   h1_mask = 1u;
  else return;  // too small: leave output wrong -> absmax signal, not a hang

  unsigned* cnt = (unsigned*)d_ws;
  ushort_t* O0  = (ushort_t*)((char*)d_ws + 1024);
  ushort_t* H1  = O0 + (size_t)FULLSLOTS * HSLOT;

  hipMemsetAsync(d_ws, 0, 1024, stream);

  lstm_persistent<<<dim3(NWG), dim3(256), 0, stream>>>(
      x, W0, b0, W1, b1, out, cnt, O0, H1, h1_mask);
}

// Round 5
// 12090.212 us; speedup vs baseline: 3.5885x; 3.5885x over previous
//
#include <hip/hip_runtime.h>

// Persistent 2-layer LSTM for MI355X (gfx950).
// 256 WGs x 256 threads (plain launch; 256 blocks <= 256 CUs => all resident).
// Each WG owns 4 hidden units (16 gate rows: 4 units x {i,f,g,o}).
// Weights pinned in VGPRs as bf16 MFMA fragments. Grid barrier per timestep.
//
// Cross-XCD h traffic uses per-access device-scope (sc1) atomics (no whole-L2
// __threadfence, which cost ~40us/step in the R1 run):
//   - h publish: LDS-staged, wave 0 stores 8B relaxed agent atomics (write-through)
//   - h consume: 8B relaxed agent atomic loads (bypass stale local L2, read LLC)
// R3 fix (kept): recurrent chunk pointers derived from the ushort base (64B
// stride), not u64 units.
// R4: grid-wide ABORT flag in the barrier — first WG to time out (~0.7ms)
// releases the whole grid, so any coherence/residency failure becomes a FAST
// reported absmax failure instead of a minutes-long run that kills the
// container before producing output.

typedef unsigned short ushort_t;
typedef unsigned long long u64_t;
typedef __attribute__((ext_vector_type(8))) short short8;   // 8 bf16 MFMA operand
typedef __attribute__((ext_vector_type(4))) float f32x4;

#define NWG    256
#define SEQ    512
#define HSLOT  32768          // 32*1024 elements per time slot
#define FULLSLOTS 513         // slot 0 = zeros, slot t+1 = h after step t
#define ABORT_IDX 240         // u32 index of abort flag inside 1KB counter region

union S8U { short8 s; u64_t u[2]; };

__device__ __forceinline__ ushort_t f2bf(float f) {
  unsigned u = __builtin_bit_cast(unsigned, f);
  u += 0x7FFFu + ((u >> 16) & 1u);      // round-to-nearest-even
  return (ushort_t)(u >> 16);
}

__device__ __forceinline__ short8 pack_bf8(f32x4 a, f32x4 b) {
  short8 r;
  r[0] = (short)f2bf(a[0]); r[1] = (short)f2bf(a[1]);
  r[2] = (short)f2bf(a[2]); r[3] = (short)f2bf(a[3]);
  r[4] = (short)f2bf(b[0]); r[5] = (short)f2bf(b[1]);
  r[6] = (short)f2bf(b[2]); r[7] = (short)f2bf(b[3]);
  return r;
}

__device__ __forceinline__ float sigm(float x) { return 1.0f / (1.0f + __expf(-x)); }
__device__ __forceinline__ float fast_tanh(float x) {
  x = fminf(fmaxf(x, -15.f), 15.f);
  float e = __expf(-2.0f * x);
  return (1.0f - e) / (1.0f + e);
}

// Barrier arrive+wait. Caller guarantees its device-visible stores are drained
// (wave holding thread 0 must have vmcnt(0) before the arrive-add).
// Spin is bounded AND cooperative: first timeout sets an agent-scope abort
// flag; all pollers break on it. Worst case = ONE ~0.7ms stall grid-wide,
// then everything free-runs to a fast (wrong, reported) finish.
__device__ __forceinline__ void bar_arrive_wait(unsigned* cnt, unsigned epoch) {
  if (threadIdx.x == 0)
    __hip_atomic_fetch_add(cnt + (blockIdx.x & 7) * 32, 1u,
                           __ATOMIC_RELAXED, __HIP_MEMORY_SCOPE_AGENT);
  if (threadIdx.x < 8) {
    const unsigned tgt = epoch * (NWG / 8);
    for (int it = 0;; ++it) {
      if (__hip_atomic_load(cnt + threadIdx.x * 32,
                            __ATOMIC_RELAXED, __HIP_MEMORY_SCOPE_AGENT) >= tgt) break;
      if ((it & 63) == 63 &&
          __hip_atomic_load(cnt + ABORT_IDX,
                            __ATOMIC_RELAXED, __HIP_MEMORY_SCOPE_AGENT) != 0) break;
      if (it >= 16384) {   // ~0.7ms @ s_sleep(1): declare failure, release grid
        __hip_atomic_store(cnt + ABORT_IDX, 1u,
                           __ATOMIC_RELAXED, __HIP_MEMORY_SCOPE_AGENT);
        break;
      }
      __builtin_amdgcn_s_sleep(1);
    }
  }
  __syncthreads();
}

// One LSTM layer over 512 steps.
//  KX    : K-extent of the x-part (512 for layer0, 1024 for layer1)
//  NCHX  : x-part K-chunks (KX/32)
//  XFP32 : x-part source is fp32 (layer0 reads x directly), else bf16 plain-cached
// Wave roles: ntile = wave&1 (batch 16-tile), khalf = wave>>1 (0: x-part K, 1: h-part K).
// MFMA: D[m][n] = sum_k Wslice[m][k]*act[n][k]; m (A row) = unit_local*4+gate, n = batch.
// C/D layout: col = lane&15 (=batch), row = (lane>>4)*4 + reg  -> reg = gate.
template<int KX, int NCHX, bool XFP32>
__device__ __forceinline__ void run_layer(
    const void* xsrc, long x_step, long x_bstride,
    const ushort_t* __restrict__ hbuf, ushort_t* __restrict__ hbuf_w, unsigned hmask,
    const float* __restrict__ W, int ldw,
    const float* __restrict__ bias,
    float* __restrict__ out, int out_h_off, int out_c_off, int write_last,
    float* red, u64_t* stage, unsigned* cnt, unsigned& epoch, int unit_base)
{
  const int lane  = threadIdx.x & 63;
  const int wave  = threadIdx.x >> 6;
  const int ntile = wave & 1;
  const int khalf = wave >> 1;
  const int wrow  = lane & 15;                      // A-frag row (gate slot m)
  const int koff  = (lane >> 4) * 8;                // A/B-frag k offset (ushorts)
  const int bb    = ntile * 16 + (lane & 15);       // batch (B row / D col)
  const int u     = unit_base + (lane >> 4);        // hidden unit for epilogue
  const int grow  = (wrow & 3) * 1024 + unit_base + (wrow >> 2); // W row: gate*1024+unit

  // ---- pin this wave's weight fragments in registers (bf16) ----
  short8 wreg[32];
  {
    const int kbase = khalf ? KX : 0;
    const int mych  = khalf ? 32 : NCHX;
    const float* ws = W + (long)grow * ldw + kbase + koff;
    #pragma unroll
    for (int ch = 0; ch < 32; ++ch) {
      if (ch < mych) {
        f32x4 v0 = *(const f32x4*)(ws + ch * 32);
        f32x4 v1 = *(const f32x4*)(ws + ch * 32 + 4);
        wreg[ch] = pack_bf8(v0, v1);
      }
    }
  }

  const float bI = bias[u];
  const float bF = bias[1024 + u];
  const float bG = bias[2048 + u];
  const float bO = bias[3072 + u];
  float c = 0.0f;

  for (int t = 0; t < SEQ; ++t) {
    f32x4 acc0 = {0.f, 0.f, 0.f, 0.f};
    f32x4 acc1 = {0.f, 0.f, 0.f, 0.f};

    if (khalf == 0) {
      if constexpr (XFP32) {
        const float* bp = (const float*)xsrc + (long)t * x_step + (long)bb * x_bstride + koff;
        #pragma unroll
        for (int ch = 0; ch < NCHX; ++ch) {
          f32x4 v0 = *(const f32x4*)(bp + ch * 32);
          f32x4 v1 = *(const f32x4*)(bp + ch * 32 + 4);
          short8 bfrag = pack_bf8(v0, v1);
          if (ch & 1) acc1 = __builtin_amdgcn_mfma_f32_16x16x32_bf16(wreg[ch], bfrag, acc1, 0, 0, 0);
          else        acc0 = __builtin_amdgcn_mfma_f32_16x16x32_bf16(wreg[ch], bfrag, acc0, 0, 0, 0);
        }
      } else {
        // write-once buffer, fully published (sc1) during previous layer -> plain cached
        const ushort_t* bp = (const ushort_t*)xsrc + (long)t * x_step + (long)bb * x_bstride + koff;
        #pragma unroll
        for (int ch = 0; ch < NCHX; ++ch) {
          short8 bfrag = *(const short8*)(bp + ch * 32);
          if (ch & 1) acc1 = __builtin_amdgcn_mfma_f32_16x16x32_bf16(wreg[ch], bfrag, acc1, 0, 0, 0);
          else        acc0 = __builtin_amdgcn_mfma_f32_16x16x32_bf16(wreg[ch], bfrag, acc0, 0, 0, 0);
        }
      }
    } else {
      // recurrent part: h_prev slot (t & hmask), device-scope loads (bypass stale L2).
      // Chunk ch covers ushorts [ch*32 + koff, +8) -> 16B at 64B stride (u64-aligned).
      const ushort_t* bp = hbuf + (long)(t & hmask) * HSLOT + bb * 1024 + koff;
      #pragma unroll
      for (int ch = 0; ch < 32; ++ch) {
        const u64_t* p = (const u64_t*)(bp + ch * 32);
        S8U f;
        f.u[0] = __hip_atomic_load(p,     __ATOMIC_RELAXED, __HIP_MEMORY_SCOPE_AGENT);
        f.u[1] = __hip_atomic_load(p + 1, __ATOMIC_RELAXED, __HIP_MEMORY_SCOPE_AGENT);
        if (ch & 1) acc1 = __builtin_amdgcn_mfma_f32_16x16x32_bf16(wreg[ch], f.s, acc1, 0, 0, 0);
        else        acc0 = __builtin_amdgcn_mfma_f32_16x16x32_bf16(wreg[ch], f.s, acc0, 0, 0, 0);
      }
      f32x4 acc = acc0 + acc1;
      *(f32x4*)&red[(ntile * 64 + lane) * 4] = acc;  // partial for cross-wave K-reduction
    }

    __syncthreads();

    if (khalf == 0) {
      f32x4 acc = acc0 + acc1;
      f32x4 oth = *(const f32x4*)&red[(ntile * 64 + lane) * 4];
      float pi = acc[0] + oth[0] + bI;
      float pf = acc[1] + oth[1] + bF;
      float pg = acc[2] + oth[2] + bG;
      float po = acc[3] + oth[3] + bO;
      float ig = sigm(pi);
      float fg = sigm(pf);
      float gg = fast_tanh(pg);
      float og = sigm(po);
      c = fg * c + ig * gg;
      float h = og * fast_tanh(c);
      ((ushort_t*)stage)[bb * 4 + (lane >> 4)] = f2bf(h);   // stage for packed publish
      if (t == SEQ - 1) {
        out[out_h_off + bb * 1024 + u] = h;      // h_n[layer]
        out[out_c_off + bb * 1024 + u] = c;      // c_n[layer]
        if (write_last) out[bb * 1024 + u] = h;  // out1[:, -1, :]
      }
    }

    __syncthreads();   // stage ready; red consumed

    // wave 0 publishes this WG's 4 units x 32 batches as 32x 8B device-scope stores
    if (threadIdx.x < 32) {
      u64_t v = stage[threadIdx.x];
      u64_t* dst = (u64_t*)(hbuf_w + (long)((t + 1) & hmask) * HSLOT
                            + (long)threadIdx.x * 1024 + unit_base);
      __hip_atomic_store(dst, v, __ATOMIC_RELAXED, __HIP_MEMORY_SCOPE_AGENT);
    }
    // drain wave 0's sc1 stores so the barrier-arrive add orders after them
    asm volatile("s_waitcnt vmcnt(0)" ::: "memory");

    ++epoch;
    bar_arrive_wait(cnt, epoch);
  }
}

__global__ __launch_bounds__(256, 1)
void lstm_persistent(const float* __restrict__ x,  const float* __restrict__ W0,
                     const float* __restrict__ b0, const float* __restrict__ W1,
                     const float* __restrict__ b1, float* __restrict__ out,
                     unsigned* cnt, ushort_t* O0, ushort_t* H1, unsigned h1_mask)
{
  __shared__ float red[512];    // cross-wave K-reduction: 2 ntiles x 64 lanes x 4 floats
  __shared__ u64_t stage[32];   // packed h publish staging: 32 batches x 4 units (bf16)
  unsigned epoch = 0;
  const int unit_base = blockIdx.x * 4;

  // zero slot 0 of both h buffers (initial hidden state), device-visible (sc1)
  int gtid = blockIdx.x * 256 + threadIdx.x;
  if (gtid < 16384) {
    __hip_atomic_store((unsigned*)O0 + gtid, 0u, __ATOMIC_RELAXED, __HIP_MEMORY_SCOPE_AGENT);
    __hip_atomic_store((unsigned*)H1 + gtid, 0u, __ATOMIC_RELAXED, __HIP_MEMORY_SCOPE_AGENT);
  }
  asm volatile("s_waitcnt vmcnt(0)" ::: "memory");
  __syncthreads();   // all waves drained before thread 0 signals
  ++epoch;
  bar_arrive_wait(cnt, epoch);

  // layer 0: combined = [x_t (fp32, K=512) ; h0_prev (bf16, K=1024)]
  run_layer<512, 16, true>(x, 512, 262144,
                           O0, O0, 0xFFFFFFFFu, W0, 1536, b0,
                           out, 32768, 98304, 0,
                           red, stage, cnt, epoch, unit_base);

  // layer 1: combined = [out0_t (= O0 slot t+1, K=1024, plain cached) ; h1_prev (bf16)]
  run_layer<1024, 32, false>((const void*)(O0 + HSLOT), HSLOT, 1024,
                             H1, H1, h1_mask, W1, 2048, b1,
                             out, 65536, 131072, 1,
                             red, stage, cnt, epoch, unit_base);
}

extern "C" void kernel_launch(void* const* d_in, const int* in_sizes, int n_in,
                              void* d_out, int out_size, void* d_ws, size_t ws_size,
                              hipStream_t stream) {
  (void)in_sizes; (void)n_in; (void)out_size;

  const float* x  = (const float*)d_in[0];
  const float* W0 = (const float*)d_in[1];
  const float* b0 = (const float*)d_in[2];
  const float* W1 = (const float*)d_in[3];
  const float* b1 = (const float*)d_in[4];
  float* out = (float*)d_out;

  // workspace layout:
  //   [0, 1024)           barrier counters (8 stripes x 128 B) + abort flag
  //   [1024, +513*64KB)   O0: layer-0 h, full 513 slots (write-once)
  //   then H1: layer-1 h, 513 slots if ws allows, else 2-slot ping-pong
  const size_t o0_bytes  = (size_t)FULLSLOTS * HSLOT * sizeof(ushort_t);
  const size_t need_full = 1024 + o0_bytes + o0_bytes;
  const size_t need_pp   = 1024 + o0_bytes + 2ull * HSLOT * sizeof(ushort_t);

  unsigned h1_mask;
  if      (ws_size >= need_full) h1_mask = 0xFFFFFFFFu;
  else if (ws_size >= need_pp)   h1_mask = 1u;
  else return;  // too small: wrong answer -> absmax signal, not a hang

  unsigned* cnt = (unsigned*)d_ws;
  ushort_t* O0  = (ushort_t*)((char*)d_ws + 1024);
  ushort_t* H1  = O0 + (size_t)FULLSLOTS * HSLOT;

  hipMemsetAsync(d_ws, 0, 1024, stream);

  lstm_persistent<<<dim3(NWG), dim3(256), 0, stream>>>(
      x, W0, b0, W1, b1, out, cnt, O0, H1, h1_mask);
}

// Round 6
// 8776.581 us; speedup vs baseline: 4.9433x; 1.3776x over previous
//
#include <hip/hip_runtime.h>

// Persistent 2-layer LSTM for MI355X (gfx950).
// R6: 256 WGs x 512 threads (8 waves = 2 batch-tiles x 4 K-quarters).
// Each WG owns 4 hidden units (16 gate rows). Weights pinned in VGPRs as bf16
// MFMA fragments (wreg[16] = 64 VGPRs/wave, half of R5 -> more h-loads in
// flight). Grid barrier per timestep (1025 total), 16 striped counters.
// Cross-XCD h traffic: relaxed agent-scope (sc1) 8B atomics, publish packed
// in-register via __shfl (no LDS stage, one less __syncthreads).

typedef unsigned short ushort_t;
typedef unsigned long long u64_t;
typedef __attribute__((ext_vector_type(8))) short short8;   // 8 bf16 MFMA operand
typedef __attribute__((ext_vector_type(4))) float f32x4;

#define NWG       256
#define NTHREADS  512
#define SEQ       512
#define HSLOT     32768        // 32*1024 elements per time slot
#define FULLSLOTS 513          // slot 0 = zeros, slot t+1 = h after step t
#define NSTRIPE   16
#define STRIDE32  64           // stripe spacing in u32 (256 B)
#define ABORT_IDX 1023         // u32 index of abort flag (4 KB counter region)

union S8U { short8 s; u64_t u[2]; };

__device__ __forceinline__ ushort_t f2bf(float f) {
  unsigned u = __builtin_bit_cast(unsigned, f);
  u += 0x7FFFu + ((u >> 16) & 1u);      // round-to-nearest-even
  return (ushort_t)(u >> 16);
}

__device__ __forceinline__ short8 pack_bf8(f32x4 a, f32x4 b) {
  short8 r;
  r[0] = (short)f2bf(a[0]); r[1] = (short)f2bf(a[1]);
  r[2] = (short)f2bf(a[2]); r[3] = (short)f2bf(a[3]);
  r[4] = (short)f2bf(b[0]); r[5] = (short)f2bf(b[1]);
  r[6] = (short)f2bf(b[2]); r[7] = (short)f2bf(b[3]);
  return r;
}

__device__ __forceinline__ float sigm(float x) { return 1.0f / (1.0f + __expf(-x)); }
__device__ __forceinline__ float fast_tanh(float x) {
  x = fminf(fmaxf(x, -15.f), 15.f);
  float e = __expf(-2.0f * x);
  return (1.0f - e) / (1.0f + e);
}

// Barrier arrive+wait. Caller guarantees its device-visible stores are drained
// before thread 0 reaches the arrive (stores drained, then __syncthreads).
// Bounded spin + grid-wide abort flag: first WG to time out (~0.7 ms) releases
// the whole grid -> coherence failure becomes a fast reported absmax failure.
__device__ __forceinline__ void bar_arrive_wait(unsigned* cnt, unsigned epoch) {
  if (threadIdx.x == 0)
    __hip_atomic_fetch_add(cnt + (blockIdx.x & (NSTRIPE - 1)) * STRIDE32, 1u,
                           __ATOMIC_RELAXED, __HIP_MEMORY_SCOPE_AGENT);
  if (threadIdx.x < NSTRIPE) {
    const unsigned tgt = epoch * (NWG / NSTRIPE);
    for (int it = 0;; ++it) {
      if (__hip_atomic_load(cnt + threadIdx.x * STRIDE32,
                            __ATOMIC_RELAXED, __HIP_MEMORY_SCOPE_AGENT) >= tgt) break;
      if ((it & 63) == 63 &&
          __hip_atomic_load(cnt + ABORT_IDX,
                            __ATOMIC_RELAXED, __HIP_MEMORY_SCOPE_AGENT) != 0) break;
      if (it >= 16384) {
        __hip_atomic_store(cnt + ABORT_IDX, 1u,
                           __ATOMIC_RELAXED, __HIP_MEMORY_SCOPE_AGENT);
        break;
      }
      __builtin_amdgcn_s_sleep(1);
    }
  }
  __syncthreads();
}

// One LSTM layer over 512 steps.
//  KX    : K-extent of the x-part (512 layer0, 1024 layer1)
//  XFP32 : x-part source is fp32 (layer0 reads x directly), else bf16 cached
// Wave roles (8 waves): ntile = wave>>2 (batch 16-tile), ksub = wave&3:
//   ksub 0,1 -> x-part K-half 0/1 (ksub 0 also runs the epilogue)
//   ksub 2,3 -> h-part K-half 0/1 (sc1 atomic loads)
// MFMA: D[m][n] = sum_k W[m][k]*act[n][k]; m = unit_local*4+gate, n = batch.
// C/D layout: col = lane&15 (=batch), row = (lane>>4)*4 + reg -> reg = gate.
template<int KX, bool XFP32>
__device__ __forceinline__ void run_layer(
    const void* xsrc, long x_step, long x_bstride,
    const ushort_t* __restrict__ hbuf, ushort_t* __restrict__ hbuf_w, unsigned hmask,
    const float* __restrict__ W, int ldw,
    const float* __restrict__ bias,
    float* __restrict__ out, int out_h_off, int out_c_off, int write_last,
    float* red, unsigned* cnt, unsigned& epoch, int unit_base)
{
  constexpr int XCH = (KX / 2) / 32;                // x chunks per x-wave (8 or 16)
  const int lane  = threadIdx.x & 63;
  const int wave  = threadIdx.x >> 6;               // 0..7
  const int ntile = wave >> 2;                      // 0,1
  const int ksub  = wave & 3;                       // 0..3
  const bool isH  = ksub >= 2;
  const int sub   = ksub & 1;

  const int wrow  = lane & 15;                      // A-frag row (gate slot m)
  const int koff  = (lane >> 4) * 8;                // A/B-frag k offset (elements)
  const int bb    = ntile * 16 + (lane & 15);       // batch (B row / D col)
  const int u     = unit_base + (lane >> 4);        // hidden unit for epilogue
  const int grow  = (wrow & 3) * 1024 + unit_base + (wrow >> 2); // W row: gate*1024+unit

  // ---- pin this wave's weight fragments in registers (bf16) ----
  short8 wreg[16];
  if (isH) {
    const float* ws = W + (long)grow * ldw + KX + sub * 512 + koff;
    #pragma unroll
    for (int ch = 0; ch < 16; ++ch) {
      f32x4 v0 = *(const f32x4*)(ws + ch * 32);
      f32x4 v1 = *(const f32x4*)(ws + ch * 32 + 4);
      wreg[ch] = pack_bf8(v0, v1);
    }
  } else {
    const float* ws = W + (long)grow * ldw + sub * (KX / 2) + koff;
    #pragma unroll
    for (int ch = 0; ch < XCH; ++ch) {
      f32x4 v0 = *(const f32x4*)(ws + ch * 32);
      f32x4 v1 = *(const f32x4*)(ws + ch * 32 + 4);
      wreg[ch] = pack_bf8(v0, v1);
    }
  }

  const float bI = bias[u];
  const float bF = bias[1024 + u];
  const float bG = bias[2048 + u];
  const float bO = bias[3072 + u];
  float c = 0.0f;

  for (int t = 0; t < SEQ; ++t) {
    f32x4 acc0 = {0.f, 0.f, 0.f, 0.f};
    f32x4 acc1 = {0.f, 0.f, 0.f, 0.f};

    if (!isH) {
      if constexpr (XFP32) {
        const float* bp = (const float*)xsrc + (long)t * x_step + (long)bb * x_bstride
                          + sub * (KX / 2) + koff;
        #pragma unroll
        for (int ch = 0; ch < XCH; ++ch) {
          f32x4 v0 = *(const f32x4*)(bp + ch * 32);
          f32x4 v1 = *(const f32x4*)(bp + ch * 32 + 4);
          short8 bfrag = pack_bf8(v0, v1);
          if (ch & 1) acc1 = __builtin_amdgcn_mfma_f32_16x16x32_bf16(wreg[ch], bfrag, acc1, 0, 0, 0);
          else        acc0 = __builtin_amdgcn_mfma_f32_16x16x32_bf16(wreg[ch], bfrag, acc0, 0, 0, 0);
        }
      } else {
        // write-once buffer published (sc1) during previous layer -> plain cached
        const ushort_t* bp = (const ushort_t*)xsrc + (long)t * x_step + (long)bb * x_bstride
                             + sub * (KX / 2) + koff;
        #pragma unroll
        for (int ch = 0; ch < XCH; ++ch) {
          short8 bfrag = *(const short8*)(bp + ch * 32);
          if (ch & 1) acc1 = __builtin_amdgcn_mfma_f32_16x16x32_bf16(wreg[ch], bfrag, acc1, 0, 0, 0);
          else        acc0 = __builtin_amdgcn_mfma_f32_16x16x32_bf16(wreg[ch], bfrag, acc0, 0, 0, 0);
        }
      }
    } else {
      // recurrent half: h_prev slot (t & hmask), device-scope 8B atomic loads.
      // Chunk ch covers ushorts [sub*512 + ch*32 + koff, +8) -> 16B at 64B stride.
      const ushort_t* bp = hbuf + (long)(t & hmask) * HSLOT + bb * 1024 + sub * 512 + koff;
      #pragma unroll
      for (int ch = 0; ch < 16; ++ch) {
        const u64_t* p = (const u64_t*)(bp + ch * 32);
        S8U f;
        f.u[0] = __hip_atomic_load(p,     __ATOMIC_RELAXED, __HIP_MEMORY_SCOPE_AGENT);
        f.u[1] = __hip_atomic_load(p + 1, __ATOMIC_RELAXED, __HIP_MEMORY_SCOPE_AGENT);
        if (ch & 1) acc1 = __builtin_amdgcn_mfma_f32_16x16x32_bf16(wreg[ch], f.s, acc1, 0, 0, 0);
        else        acc0 = __builtin_amdgcn_mfma_f32_16x16x32_bf16(wreg[ch], f.s, acc0, 0, 0, 0);
      }
    }

    // 4-way cross-wave K reduction: ksub 1..3 write partials, ksub 0 sums.
    if (ksub != 0) {
      f32x4 a = acc0 + acc1;
      *(f32x4*)&red[((ntile * 3 + (ksub - 1)) * 64 + lane) * 4] = a;
    }

    __syncthreads();

    if (ksub == 0) {
      f32x4 a = acc0 + acc1;
      #pragma unroll
      for (int j = 0; j < 3; ++j)
        a += *(const f32x4*)&red[((ntile * 3 + j) * 64 + lane) * 4];
      float pi = a[0] + bI;
      float pf = a[1] + bF;
      float pg = a[2] + bG;
      float po = a[3] + bO;
      float ig = sigm(pi);
      float fg = sigm(pf);
      float gg = fast_tanh(pg);
      float og = sigm(po);
      c = fg * c + ig * gg;
      float h = og * fast_tanh(c);

      // pack 4 units per batch in-register: lane L holds (b15=L&15, uloc=L>>4);
      // target lane L<16 needs lanes L, L+16, L+32, L+48.
      unsigned v  = f2bf(h);
      unsigned v1 = __shfl(v, (lane & 15) + 16);
      unsigned v2 = __shfl(v, (lane & 15) + 32);
      unsigned v3 = __shfl(v, (lane & 15) + 48);

      if (t == SEQ - 1) {
        out[out_h_off + bb * 1024 + u] = h;      // h_n[layer]
        out[out_c_off + bb * 1024 + u] = c;      // c_n[layer]
        if (write_last) out[bb * 1024 + u] = h;  // out1[:, -1, :]
      }

      if (lane < 16) {
        u64_t val = (u64_t)(v & 0xFFFFu) | ((u64_t)(v1 & 0xFFFFu) << 16)
                  | ((u64_t)(v2 & 0xFFFFu) << 32) | ((u64_t)(v3 & 0xFFFFu) << 48);
        u64_t* dst = (u64_t*)(hbuf_w + (long)((t + 1) & hmask) * HSLOT
                              + (long)bb * 1024 + unit_base);
        __hip_atomic_store(dst, val, __ATOMIC_RELAXED, __HIP_MEMORY_SCOPE_AGENT);
      }
      // drain this epilogue wave's sc1 stores; both epilogue waves drain before
      // the __syncthreads below, so thread 0's arrive orders after all publishes
      asm volatile("s_waitcnt vmcnt(0)" ::: "memory");
    }

    __syncthreads();
    ++epoch;
    bar_arrive_wait(cnt, epoch);
  }
}

__global__ __launch_bounds__(NTHREADS, 1)
void lstm_persistent(const float* __restrict__ x,  const float* __restrict__ W0,
                     const float* __restrict__ b0, const float* __restrict__ W1,
                     const float* __restrict__ b1, float* __restrict__ out,
                     unsigned* cnt, ushort_t* O0, ushort_t* H1, unsigned h1_mask)
{
  __shared__ float red[1536];   // 2 ntiles x 3 partial-waves x 64 lanes x 4 floats
  unsigned epoch = 0;
  const int unit_base = blockIdx.x * 4;

  // zero slot 0 of both h buffers (initial hidden state), device-visible (sc1)
  int gtid = blockIdx.x * NTHREADS + threadIdx.x;
  if (gtid < 16384) {
    __hip_atomic_store((unsigned*)O0 + gtid, 0u, __ATOMIC_RELAXED, __HIP_MEMORY_SCOPE_AGENT);
    __hip_atomic_store((unsigned*)H1 + gtid, 0u, __ATOMIC_RELAXED, __HIP_MEMORY_SCOPE_AGENT);
  }
  asm volatile("s_waitcnt vmcnt(0)" ::: "memory");
  __syncthreads();   // all waves drained before thread 0 signals
  ++epoch;
  bar_arrive_wait(cnt, epoch);

  // layer 0: combined = [x_t (fp32, K=512) ; h0_prev (bf16, K=1024)]
  run_layer<512, true>(x, 512, 262144,
                       O0, O0, 0xFFFFFFFFu, W0, 1536, b0,
                       out, 32768, 98304, 0,
                       red, cnt, epoch, unit_base);

  // layer 1: combined = [out0_t (= O0 slot t+1, K=1024, cached) ; h1_prev (bf16)]
  run_layer<1024, false>((const void*)(O0 + HSLOT), HSLOT, 1024,
                         H1, H1, h1_mask, W1, 2048, b1,
                         out, 65536, 131072, 1,
                         red, cnt, epoch, unit_base);
}

extern "C" void kernel_launch(void* const* d_in, const int* in_sizes, int n_in,
                              void* d_out, int out_size, void* d_ws, size_t ws_size,
                              hipStream_t stream) {
  (void)in_sizes; (void)n_in; (void)out_size;

  const float* x  = (const float*)d_in[0];
  const float* W0 = (const float*)d_in[1];
  const float* b0 = (const float*)d_in[2];
  const float* W1 = (const float*)d_in[3];
  const float* b1 = (const float*)d_in[4];
  float* out = (float*)d_out;

  // workspace layout:
  //   [0, 4096)           barrier counters (16 stripes x 256 B) + abort flag
  //   [4096, +513*64KB)   O0: layer-0 h, full 513 slots (write-once)
  //   then H1: layer-1 h, 513 slots if ws allows, else 2-slot ping-pong
  const size_t o0_bytes  = (size_t)FULLSLOTS * HSLOT * sizeof(ushort_t);
  const size_t need_full = 4096 + o0_bytes + o0_bytes;
  const size_t need_pp   = 4096 + o0_bytes + 2ull * HSLOT * sizeof(ushort_t);

  unsigned h1_mask;
  if      (ws_size >= need_full) h1_mask = 0xFFFFFFFFu;
  else if (ws_size >= need_pp)   h1_mask = 1u;
  else return;  // too small: wrong answer -> absmax signal, not a hang

  unsigned* cnt = (unsigned*)d_ws;
  ushort_t* O0  = (ushort_t*)((char*)d_ws + 4096);
  ushort_t* H1  = O0 + (size_t)FULLSLOTS * HSLOT;

  hipMemsetAsync(d_ws, 0, 4096, stream);

  lstm_persistent<<<dim3(NWG), dim3(NTHREADS), 0, stream>>>(
      x, W0, b0, W1, b1, out, cnt, O0, H1, h1_mask);
}

// Round 7
// 3598.563 us; speedup vs baseline: 12.0564x; 2.4389x over previous
//
#include <hip/hip_runtime.h>

// Persistent pipelined 2-layer LSTM for MI355X (gfx950).
// R7: 256 WGs x 512 threads; WGs 0..127 run layer 0, WGs 128..255 run layer 1
// skewed by one epoch (wavefront pipelining) -> 514 grid barriers total.
// Each WG owns 8 hidden units (32 gate rows = 2 MFMA M-tiles). Weights pinned
// in VGPRs as bf16 MFMA fragments.
// Coherence scheme:
//   - h publish: sc1 (relaxed agent) 8B atomic stores -> LLC (write-through)
//   - h/x consume: PLAIN cached 16B loads. Safe because kernel-launch acquire
//     invalidates L2s and every slot address is first touched per-XCD strictly
//     after its production (full 513-slot buffers, no address reuse in-kernel).
//     16 WGs/XCD share each slot line in L2.
//   - barrier: arrive-adds on 16 stripes; only master WG polls stripes, then
//     publishes epoch to a separate read-only release line polled by 1 thr/WG.
// Bounded spins + grid abort flag: failure = fast reported absmax, not a hang.

typedef unsigned short ushort_t;
typedef unsigned long long u64_t;
typedef __attribute__((ext_vector_type(8))) short short8;   // 8 bf16 MFMA operand
typedef __attribute__((ext_vector_type(4))) float f32x4;

#define NWG       256
#define NTHREADS  512
#define SEQ       512
#define HSLOT     32768        // 32*1024 elements per time slot
#define FULLSLOTS 513          // slot 0 = zeros, slot t+1 = h after step t
#define NSTRIPE   16
#define STRIDE32  64           // stripe spacing in u32 (256 B)
#define REL_IDX   992          // release word (own 128B line, never hit by adds)
#define ABORT_IDX 1000         // same line as release -> abort check is free

__device__ __forceinline__ ushort_t f2bf(float f) {
  unsigned u = __builtin_bit_cast(unsigned, f);
  u += 0x7FFFu + ((u >> 16) & 1u);      // round-to-nearest-even
  return (ushort_t)(u >> 16);
}

__device__ __forceinline__ short8 pack_bf8(f32x4 a, f32x4 b) {
  short8 r;
  r[0] = (short)f2bf(a[0]); r[1] = (short)f2bf(a[1]);
  r[2] = (short)f2bf(a[2]); r[3] = (short)f2bf(a[3]);
  r[4] = (short)f2bf(b[0]); r[5] = (short)f2bf(b[1]);
  r[6] = (short)f2bf(b[2]); r[7] = (short)f2bf(b[3]);
  return r;
}

__device__ __forceinline__ float sigm(float x) { return 1.0f / (1.0f + __expf(-x)); }
__device__ __forceinline__ float fast_tanh(float x) {
  x = fminf(fmaxf(x, -15.f), 15.f);
  float e = __expf(-2.0f * x);
  return (1.0f - e) / (1.0f + e);
}

// Grid barrier, master-release design. Caller's publishing waves drained vmcnt
// before the leading __syncthreads, so thread 0's arrive orders after publish.
__device__ __forceinline__ void bar_sync(unsigned* cnt, unsigned epoch, bool master) {
  __syncthreads();
  if (threadIdx.x == 0)
    __hip_atomic_fetch_add(cnt + (blockIdx.x & (NSTRIPE - 1)) * STRIDE32, 1u,
                           __ATOMIC_RELAXED, __HIP_MEMORY_SCOPE_AGENT);
  if (master) {
    if (threadIdx.x < NSTRIPE) {
      const unsigned tgt = epoch * (NWG / NSTRIPE);
      for (int it = 0;; ++it) {
        if (__hip_atomic_load(cnt + threadIdx.x * STRIDE32,
                              __ATOMIC_RELAXED, __HIP_MEMORY_SCOPE_AGENT) >= tgt) break;
        if ((it & 63) == 63 &&
            __hip_atomic_load(cnt + ABORT_IDX,
                              __ATOMIC_RELAXED, __HIP_MEMORY_SCOPE_AGENT) != 0) break;
        if (it >= 20000) {
          __hip_atomic_store(cnt + ABORT_IDX, 1u,
                             __ATOMIC_RELAXED, __HIP_MEMORY_SCOPE_AGENT);
          break;
        }
        __builtin_amdgcn_s_sleep(1);
      }
    }
    __syncthreads();   // all stripe pollers done
    if (threadIdx.x == 0)
      __hip_atomic_store(cnt + REL_IDX, epoch,
                         __ATOMIC_RELAXED, __HIP_MEMORY_SCOPE_AGENT);
  } else {
    if (threadIdx.x == 0) {
      for (int it = 0;; ++it) {
        if (__hip_atomic_load(cnt + REL_IDX,
                              __ATOMIC_RELAXED, __HIP_MEMORY_SCOPE_AGENT) >= epoch) break;
        if ((it & 63) == 63 &&
            __hip_atomic_load(cnt + ABORT_IDX,
                              __ATOMIC_RELAXED, __HIP_MEMORY_SCOPE_AGENT) != 0) break;
        if (it >= 20000) {
          __hip_atomic_store(cnt + ABORT_IDX, 1u,
                             __ATOMIC_RELAXED, __HIP_MEMORY_SCOPE_AGENT);
          break;
        }
        __builtin_amdgcn_s_sleep(1);
      }
    }
  }
  __syncthreads();
}

// One LSTM layer over 512 steps (this role's half of the pipelined grid).
//  KX    : K-extent of the x-part (512 layer0, 1024 layer1)
//  XFP32 : x-part source is fp32 (layer0 reads x directly), else bf16 cached
// 8 waves: ntile = wave>>2 (batch 16-tile), ksub = wave&3:
//   ksub 0,1 -> x-part K-halves (ksub 0 runs the epilogue); ksub 2,3 -> h-part.
// Each wave computes 2 M-tiles (8 units x 4 gates = 32 rows).
// MFMA 16x16x32: D[m][n], m = unit_local*4+gate, n = batch.
// C/D layout: col = lane&15 (=batch), row = (lane>>4)*4 + reg -> reg = gate.
template<int KX, bool XFP32>
__device__ __forceinline__ void run_layer(
    const void* xsrc, long x_step, long x_bstride,
    const ushort_t* __restrict__ hbuf, ushort_t* __restrict__ hbuf_w,
    const float* __restrict__ W, int ldw,
    const float* __restrict__ bias,
    float* __restrict__ out, int out_h_off, int out_c_off, int write_last,
    float* red, unsigned* cnt, unsigned& epoch, int unit_base, bool master)
{
  constexpr int XCH = (KX / 2) / 32;                // x chunks per x-wave (8 or 16)
  const int lane  = threadIdx.x & 63;
  const int wave  = threadIdx.x >> 6;               // 0..7
  const int ntile = wave >> 2;                      // 0,1
  const int ksub  = wave & 3;                       // 0..3
  const bool isH  = ksub >= 2;
  const int sub   = ksub & 1;

  const int wrow  = lane & 15;                      // A-frag row within M-tile
  const int koff  = (lane >> 4) * 8;                // A/B-frag k offset (elements)
  const int bb    = ntile * 16 + (lane & 15);       // batch (B row / D col)

  const int mych  = isH ? 16 : XCH;
  const int kbase = isH ? (KX + sub * 512) : (sub * (KX / 2));

  // ---- pin this wave's weight fragments in registers (bf16), 2 M-tiles ----
  short8 wreg[2][16];
  #pragma unroll
  for (int mt = 0; mt < 2; ++mt) {
    const int grow = (wrow & 3) * 1024 + unit_base + mt * 4 + (wrow >> 2);
    const float* ws = W + (long)grow * ldw + kbase + koff;
    #pragma unroll
    for (int ch = 0; ch < 16; ++ch) {
      if (ch < mych) {
        f32x4 v0 = *(const f32x4*)(ws + ch * 32);
        f32x4 v1 = *(const f32x4*)(ws + ch * 32 + 4);
        wreg[mt][ch] = pack_bf8(v0, v1);
      }
    }
  }

  const int u0 = unit_base + (lane >> 4);
  float bI[2], bF[2], bG[2], bO[2];
  #pragma unroll
  for (int mt = 0; mt < 2; ++mt) {
    const int u = u0 + mt * 4;
    bI[mt] = bias[u];        bF[mt] = bias[1024 + u];
    bG[mt] = bias[2048 + u]; bO[mt] = bias[3072 + u];
  }
  float c[2] = {0.f, 0.f};

  for (int t = 0; t < SEQ; ++t) {
    f32x4 acc[2] = {{0.f,0.f,0.f,0.f},{0.f,0.f,0.f,0.f}};

    if (!isH) {
      if constexpr (XFP32) {
        const float* bp = (const float*)xsrc + (long)t * x_step + (long)bb * x_bstride
                          + kbase + koff;
        f32x4 xv[2 * XCH];
        #pragma unroll
        for (int ch = 0; ch < XCH; ++ch) {
          xv[2*ch]   = *(const f32x4*)(bp + ch * 32);
          xv[2*ch+1] = *(const f32x4*)(bp + ch * 32 + 4);
        }
        #pragma unroll
        for (int ch = 0; ch < XCH; ++ch) {
          short8 bf = pack_bf8(xv[2*ch], xv[2*ch+1]);
          acc[0] = __builtin_amdgcn_mfma_f32_16x16x32_bf16(wreg[0][ch], bf, acc[0], 0, 0, 0);
          acc[1] = __builtin_amdgcn_mfma_f32_16x16x32_bf16(wreg[1][ch], bf, acc[1], 0, 0, 0);
        }
      } else {
        const ushort_t* bp = (const ushort_t*)xsrc + (long)t * x_step + (long)bb * x_bstride
                             + kbase + koff;
        short8 xv[16];
        #pragma unroll
        for (int ch = 0; ch < 16; ++ch) xv[ch] = *(const short8*)(bp + ch * 32);
        #pragma unroll
        for (int ch = 0; ch < 16; ++ch) {
          acc[0] = __builtin_amdgcn_mfma_f32_16x16x32_bf16(wreg[0][ch], xv[ch], acc[0], 0, 0, 0);
          acc[1] = __builtin_amdgcn_mfma_f32_16x16x32_bf16(wreg[1][ch], xv[ch], acc[1], 0, 0, 0);
        }
      }
    } else {
      // recurrent half: h_prev slot t, plain cached 16B loads (L2-shared per XCD)
      const ushort_t* bp = hbuf + (long)t * HSLOT + (long)bb * 1024 + sub * 512 + koff;
      short8 hv[16];
      #pragma unroll
      for (int ch = 0; ch < 16; ++ch) hv[ch] = *(const short8*)(bp + ch * 32);
      #pragma unroll
      for (int ch = 0; ch < 16; ++ch) {
        acc[0] = __builtin_amdgcn_mfma_f32_16x16x32_bf16(wreg[0][ch], hv[ch], acc[0], 0, 0, 0);
        acc[1] = __builtin_amdgcn_mfma_f32_16x16x32_bf16(wreg[1][ch], hv[ch], acc[1], 0, 0, 0);
      }
    }

    // cross-wave K reduction: ksub 1..3 write partials (2 M-tiles), ksub 0 sums
    if (ksub != 0) {
      #pragma unroll
      for (int mt = 0; mt < 2; ++mt)
        *(f32x4*)&red[(((ntile * 3 + (ksub - 1)) * 2 + mt) * 64 + lane) * 4] = acc[mt];
    }

    __syncthreads();

    if (ksub == 0) {
      u64_t pk[2];
      float hh[2];
      #pragma unroll
      for (int mt = 0; mt < 2; ++mt) {
        f32x4 a = acc[mt];
        #pragma unroll
        for (int j = 0; j < 3; ++j)
          a += *(const f32x4*)&red[(((ntile * 3 + j) * 2 + mt) * 64 + lane) * 4];
        float pi = a[0] + bI[mt], pf = a[1] + bF[mt];
        float pg = a[2] + bG[mt], po = a[3] + bO[mt];
        float ig = sigm(pi), fg = sigm(pf), gg = fast_tanh(pg), og = sigm(po);
        c[mt] = fg * c[mt] + ig * gg;
        float h = og * fast_tanh(c[mt]);
        hh[mt] = h;
        // pack 4 units/batch in-register: target lane L<16 gathers L, L+16, L+32, L+48
        unsigned v  = f2bf(h);
        unsigned v1 = __shfl((int)v, (lane & 15) + 16);
        unsigned v2 = __shfl((int)v, (lane & 15) + 32);
        unsigned v3 = __shfl((int)v, (lane & 15) + 48);
        pk[mt] = (u64_t)(v & 0xFFFFu) | ((u64_t)(v1 & 0xFFFFu) << 16)
               | ((u64_t)(v2 & 0xFFFFu) << 32) | ((u64_t)(v3 & 0xFFFFu) << 48);
      }

      if (t == SEQ - 1) {
        #pragma unroll
        for (int mt = 0; mt < 2; ++mt) {
          const int u = u0 + mt * 4;
          out[out_h_off + bb * 1024 + u] = hh[mt];      // h_n[layer]
          out[out_c_off + bb * 1024 + u] = c[mt];       // c_n[layer]
          if (write_last) out[bb * 1024 + u] = hh[mt];  // out1[:, -1, :]
        }
      }

      if (lane < 16) {
        u64_t* dst = (u64_t*)(hbuf_w + (long)(t + 1) * HSLOT + (long)bb * 1024 + unit_base);
        __hip_atomic_store(dst,     pk[0], __ATOMIC_RELAXED, __HIP_MEMORY_SCOPE_AGENT);
        __hip_atomic_store(dst + 1, pk[1], __ATOMIC_RELAXED, __HIP_MEMORY_SCOPE_AGENT);
      }
      // drain sc1 publishes before the barrier's __syncthreads -> arrive
      asm volatile("s_waitcnt vmcnt(0)" ::: "memory");
    }

    ++epoch;
    bar_sync(cnt, epoch, master);
  }
}

__global__ __launch_bounds__(NTHREADS, 2)
void lstm_persistent(const float* __restrict__ x,  const float* __restrict__ W0,
                     const float* __restrict__ b0, const float* __restrict__ W1,
                     const float* __restrict__ b1, float* __restrict__ out,
                     unsigned* cnt, ushort_t* O0, ushort_t* H1)
{
  __shared__ float red[3072];   // 2 ntiles x 3 partial-waves x 2 M-tiles x 64 x 4
  unsigned epoch = 0;
  const int  role      = (int)(blockIdx.x >> 7);      // 0: layer0, 1: layer1
  const int  unit_base = (int)(blockIdx.x & 127) * 8;
  const bool master    = (blockIdx.x == 0);

  // zero slot 0 of both h buffers (initial hidden state), device-visible (sc1)
  int gtid = (int)blockIdx.x * NTHREADS + threadIdx.x;
  if (gtid < 16384) {
    __hip_atomic_store((unsigned*)O0 + gtid, 0u, __ATOMIC_RELAXED, __HIP_MEMORY_SCOPE_AGENT);
    __hip_atomic_store((unsigned*)H1 + gtid, 0u, __ATOMIC_RELAXED, __HIP_MEMORY_SCOPE_AGENT);
  }
  asm volatile("s_waitcnt vmcnt(0)" ::: "memory");
  ++epoch;
  bar_sync(cnt, epoch, master);

  if (role == 0) {
    // layer 0: combined = [x_t (fp32, K=512) ; h0_prev (bf16, K=1024)]
    // epochs 2..513 = steps 0..511; then one trailing idle epoch (514)
    run_layer<512, true>(x, 512, 262144,
                         O0, O0, W0, 1536, b0,
                         out, 32768, 98304, 0,
                         red, cnt, epoch, unit_base, master);
    ++epoch;
    bar_sync(cnt, epoch, master);
  } else {
    // layer 1 skewed one epoch: idle epoch 2, then steps 0..511 on epochs 3..514.
    // step t reads O0 slot t+1 (produced by layer 0 at epoch t+2, one barrier
    // earlier) and H1 slot t (produced by itself one barrier earlier).
    ++epoch;
    bar_sync(cnt, epoch, false);
    run_layer<1024, false>((const void*)(O0 + HSLOT), HSLOT, 1024,
                           H1, H1, W1, 2048, b1,
                           out, 65536, 131072, 1,
                           red, cnt, epoch, unit_base, false);
  }
}

extern "C" void kernel_launch(void* const* d_in, const int* in_sizes, int n_in,
                              void* d_out, int out_size, void* d_ws, size_t ws_size,
                              hipStream_t stream) {
  (void)in_sizes; (void)n_in; (void)out_size;

  const float* x  = (const float*)d_in[0];
  const float* W0 = (const float*)d_in[1];
  const float* b0 = (const float*)d_in[2];
  const float* W1 = (const float*)d_in[3];
  const float* b1 = (const float*)d_in[4];
  float* out = (float*)d_out;

  // workspace layout:
  //   [0, 4096)           barrier stripes (16 x 256 B) + release + abort
  //   [4096, +513*64KB)   O0: layer-0 h, full 513 slots (write-once)
  //   [.., +513*64KB)     H1: layer-1 h, full 513 slots (write-once)
  const size_t o0_bytes = (size_t)FULLSLOTS * HSLOT * sizeof(ushort_t);
  const size_t need     = 4096 + 2 * o0_bytes;
  if (ws_size < need) return;  // wrong answer -> absmax signal, not a hang

  unsigned* cnt = (unsigned*)d_ws;
  ushort_t* O0  = (ushort_t*)((char*)d_ws + 4096);
  ushort_t* H1  = O0 + (size_t)FULLSLOTS * HSLOT;

  hipMemsetAsync(d_ws, 0, 4096, stream);

  lstm_persistent<<<dim3(NWG), dim3(NTHREADS), 0, stream>>>(
      x, W0, b0, W1, b1, out, cnt, O0, H1);
}